// Round 11
// baseline (182.158 us; speedup 1.0000x reference)
//
#include <hip/hip_runtime.h>

#define N_NODES 100000
#define N_EDGES 1600000
#define HID 150
#define KPAD 160
#define OUTF 64
#define BSH 9                          // 512 nodes per bucket
#define BUKN 512                       // nodes per bucket
#define NBUK ((N_NODES + BUKN - 1) / BUKN)   // 196 buckets
#define TILE 4096                      // edges per partition tile
#define NTILE ((N_EDGES + TILE - 1) / TILE)  // 391 tiles

typedef short bf16x8 __attribute__((ext_vector_type(8)));
typedef float f32x4 __attribute__((ext_vector_type(4)));

__device__ __forceinline__ unsigned short f2bf(float f) {
    union { float f; unsigned u; } v; v.f = f;
    unsigned r = (v.u + 0x7FFFu + ((v.u >> 16) & 1u)) >> 16;
    return (unsigned short)r;
}

__device__ __forceinline__ float bf2f(unsigned short b) {
    union { unsigned u; float f; } v;
    v.u = ((unsigned)b) << 16;
    return v.f;
}

// ---------------- prep: pad x -> x4, bucket histogram of dst, W1t/W2T pack ----------------
__global__ __launch_bounds__(256) void k_prep(const float* __restrict__ x,
                                              float4* __restrict__ x4,
                                              const int* __restrict__ dst,
                                              int* __restrict__ bukcnt,
                                              const float* __restrict__ W1s,
                                              const float* __restrict__ W1n,
                                              const float* __restrict__ b1,
                                              const float* __restrict__ W2s,
                                              const float* __restrict__ W2n,
                                              float* __restrict__ W1t,
                                              unsigned short* __restrict__ W2T) {
    __shared__ int cnt[NBUK];
    int tid = threadIdx.x;
    for (int i = tid; i < NBUK; i += 256) cnt[i] = 0;
    int idx = blockIdx.x * 256 + tid;
    if (idx < N_NODES)
        x4[idx] = make_float4(x[idx * 3 + 0], x[idx * 3 + 1], x[idx * 3 + 2], 0.0f);
    if (idx < KPAD) {
        int k = idx;
        bool ok = (k < HID);
        W1t[k * 8 + 0] = ok ? W1s[0 * HID + k] : 0.0f;
        W1t[k * 8 + 1] = ok ? W1s[1 * HID + k] : 0.0f;
        W1t[k * 8 + 2] = ok ? W1s[2 * HID + k] : 0.0f;
        W1t[k * 8 + 3] = ok ? b1[k] : 0.0f;
        W1t[k * 8 + 4] = ok ? W1n[0 * HID + k] : 0.0f;
        W1t[k * 8 + 5] = ok ? W1n[1 * HID + k] : 0.0f;
        W1t[k * 8 + 6] = ok ? W1n[2 * HID + k] : 0.0f;
        W1t[k * 8 + 7] = 0.0f;
    }
    if (idx < 128 * KPAD) {
        int c = idx / KPAD, k = idx - c * KPAD;
        float v = 0.0f;
        if (k < HID) v = (c < 64) ? W2s[k * 64 + c] : W2n[k * 64 + (c - 64)];
        W2T[idx] = f2bf(v);
    }
    __syncthreads();
    int e0 = blockIdx.x * TILE;
    #pragma unroll
    for (int j = 0; j < 16; ++j) {
        int e = e0 + tid + j * 256;
        if (e < N_EDGES) atomicAdd(&cnt[dst[e] >> BSH], 1);
    }
    __syncthreads();
    for (int i = tid; i < NBUK; i += 256)
        if (cnt[i]) atomicAdd(&bukcnt[i], cnt[i]);
}

// ---------------- bucket scan: bukcnt -> bukoff (exclusive), zero bukcur ----------------
__global__ __launch_bounds__(256) void k_bukscan(const int* __restrict__ bukcnt,
                                                 int* __restrict__ bukoff,
                                                 int* __restrict__ bukcur,
                                                 int* __restrict__ row_start) {
    __shared__ int sh[256];
    int t = threadIdx.x;
    int v = (t < NBUK) ? bukcnt[t] : 0;
    sh[t] = v;
    __syncthreads();
    for (int o = 1; o < 256; o <<= 1) {
        int a = sh[t];
        int ap = (t >= o) ? sh[t - o] : 0;
        __syncthreads();
        sh[t] = a + ap;
        __syncthreads();
    }
    if (t < NBUK) { bukoff[t] = sh[t] - v; bukcur[t] = 0; }
    if (t == 255) {
        bukoff[NBUK] = sh[NBUK - 1];
        row_start[N_NODES] = sh[NBUK - 1];
    }
}

// ---------------- multisplit partition: direct bucket-segment writes ----------------
__global__ __launch_bounds__(256) void k_part(const int* __restrict__ src,
                                              const int* __restrict__ dst,
                                              const int* __restrict__ bukoff,
                                              int* __restrict__ bukcur,
                                              unsigned int* __restrict__ pairbuf) {
    __shared__ int cnt[NBUK];
    __shared__ int gbase[NBUK];
    int tid = threadIdx.x;
    int e0 = blockIdx.x * TILE;
    int n = min(TILE, N_EDGES - e0);

    for (int i = tid; i < NBUK; i += 256) cnt[i] = 0;
    __syncthreads();

    int myb[16];
    int mypos[16];
    unsigned int myv[16];
    #pragma unroll
    for (int j = 0; j < 16; ++j) {
        int idx = tid + j * 256;
        myb[j] = -1;
        if (idx < n) {
            int s = src[e0 + idx];
            int d = dst[e0 + idx];
            int b = d >> BSH;
            myb[j] = b;
            myv[j] = ((unsigned int)(d & (BUKN - 1)) << 17) | (unsigned int)s;
            mypos[j] = atomicAdd(&cnt[b], 1);
        }
    }
    __syncthreads();

    if (tid < NBUK) {
        int c = cnt[tid];
        gbase[tid] = c ? (bukoff[tid] + atomicAdd(&bukcur[tid], c)) : 0;
    }
    __syncthreads();

    #pragma unroll
    for (int j = 0; j < 16; ++j) {
        if (myb[j] >= 0)
            pairbuf[gbase[myb[j]] + mypos[j]] = myv[j];
    }
}

// ---------------- merged per-bucket: hist + x-mean (layer1 agg) + scan + scatter --------
// 512 threads: thread t owns node n0+t.
__global__ __launch_bounds__(512) void k_fine(const int* __restrict__ bukoff,
                                              const unsigned int* __restrict__ pairbuf,
                                              const float4* __restrict__ x4,
                                              int* __restrict__ row_start,
                                              float* __restrict__ invd,
                                              int* __restrict__ csr_src,
                                              float4* __restrict__ hn4) {
    __shared__ int deg[BUKN];        // counts, later reused as scatter cursors
    __shared__ float sx[BUKN][4];    // x feature accumulators (8 KB)
    __shared__ int sc[BUKN];         // scan workspace
    int tid = threadIdx.x;
    int b = blockIdx.x;
    int n0 = b << BSH;
    int lo = bukoff[b], hi = bukoff[b + 1];

    deg[tid] = 0;
    sx[tid][0] = 0.f; sx[tid][1] = 0.f; sx[tid][2] = 0.f;
    __syncthreads();

    // pass 1: degree histogram + x-feature accumulation (layer-1 aggregation)
    for (int i = lo + tid; i < hi; i += 512) {
        unsigned int v = pairbuf[i];
        int dl = v >> 17;
        int s = (int)(v & 0x1FFFF);
        atomicAdd(&deg[dl], 1);
        float4 xv = x4[s];
        atomicAdd(&sx[dl][0], xv.x);
        atomicAdd(&sx[dl][1], xv.y);
        atomicAdd(&sx[dl][2], xv.z);
    }
    __syncthreads();

    // 512-wide exclusive scan of deg
    int d = deg[tid];
    sc[tid] = d;
    __syncthreads();
    for (int o = 1; o < 512; o <<= 1) {
        int a = sc[tid];
        int ap = (tid >= o) ? sc[tid - o] : 0;
        __syncthreads();
        sc[tid] = a + ap;
        __syncthreads();
    }
    int r = lo + sc[tid] - d;
    int node = n0 + tid;
    float idv = 1.0f / fmaxf((float)d, 1.0f);
    if (node < N_NODES) {
        row_start[node] = r;
        invd[node] = idv;
        hn4[node] = make_float4(sx[tid][0] * idv, sx[tid][1] * idv, sx[tid][2] * idv, 0.0f);
    }
    __syncthreads();
    deg[tid] = r;     // reuse as cursor
    __syncthreads();

    // pass 2: scatter to csr (bucket-confined dense writes)
    for (int i = lo + tid; i < hi; i += 512) {
        unsigned int v = pairbuf[i];
        int dl = v >> 17;
        int ofs = atomicAdd(&deg[dl], 1);
        csr_src[ofs] = (int)(v & 0x1FFFF);
    }
}

// ---------------- fused layer1 + layer2 GEMM via bf16 MFMA ----------------
// Writes one bf16 row per node: ob[node][0..63] = self+b2, ob[node][64..127] = p
#define SHK 168
__global__ __launch_bounds__(256, 4) void k_gemm(
        const float4* __restrict__ x4, const float4* __restrict__ hn4,
        const float* __restrict__ W1t,
        const unsigned short* __restrict__ W2T,
        const float* __restrict__ b2,
        unsigned short* __restrict__ ob) {
    __shared__ unsigned short shA[64 * SHK];   // 21.5 KB
    const int n0 = blockIdx.x * 64;
    const int tid = threadIdx.x;

    {
        int n = tid & 63;
        int node = n0 + n;
        int kbase = 2 * (tid >> 6);
        float4 xs = make_float4(0.f, 0.f, 0.f, 0.f);
        float4 xn = make_float4(0.f, 0.f, 0.f, 0.f);
        if (node < N_NODES) { xs = x4[node]; xn = hn4[node]; }
        #pragma unroll 4
        for (int j = 0; j < 20; ++j) {
            int k = kbase + 8 * j;
            float4 wa0 = *(const float4*)&W1t[k * 8 + 0];
            float4 wb0 = *(const float4*)&W1t[k * 8 + 4];
            float4 wa1 = *(const float4*)&W1t[(k + 1) * 8 + 0];
            float4 wb1 = *(const float4*)&W1t[(k + 1) * 8 + 4];
            float h0 = wa0.w + xs.x * wa0.x + xs.y * wa0.y + xs.z * wa0.z
                             + xn.x * wb0.x + xn.y * wb0.y + xn.z * wb0.z;
            float h1 = wa1.w + xs.x * wa1.x + xs.y * wa1.y + xs.z * wa1.z
                             + xn.x * wb1.x + xn.y * wb1.y + xn.z * wb1.z;
            h0 = fmaxf(h0, 0.0f);
            h1 = fmaxf(h1, 0.0f);
            unsigned int pk = (unsigned int)f2bf(h0) | ((unsigned int)f2bf(h1) << 16);
            *(unsigned int*)&shA[n * SHK + k] = pk;
        }
    }
    __syncthreads();

    const int lane = tid & 63;
    const int w = tid >> 6;
    const int c16 = lane & 15;
    const int quad = lane >> 4;
    const int ko = quad * 8;

    f32x4 acc[8];
    #pragma unroll
    for (int t = 0; t < 8; ++t) acc[t] = (f32x4){0.f, 0.f, 0.f, 0.f};

    #pragma unroll
    for (int ks = 0; ks < 5; ++ks) {
        int k0 = ks * 32;
        bf16x8 a = *(const bf16x8*)&shA[(w * 16 + c16) * SHK + k0 + ko];
        #pragma unroll
        for (int t = 0; t < 8; ++t) {
            bf16x8 b = *(const bf16x8*)&W2T[(t * 16 + c16) * KPAD + k0 + ko];
            acc[t] = __builtin_amdgcn_mfma_f32_16x16x32_bf16(a, b, acc[t], 0, 0, 0);
        }
    }

    const int rbase = n0 + w * 16 + quad * 4;
    #pragma unroll
    for (int t = 0; t < 8; ++t) {
        int cc = t * 16 + c16;
        float badd = (t < 4) ? b2[cc] : 0.0f;
        #pragma unroll
        for (int i = 0; i < 4; ++i) {
            int node = rbase + i;
            if (node < N_NODES) ob[(size_t)node * 128 + cc] = f2bf(acc[t][i] + badd);
        }
    }
}

// ---------------- layer-2 pull: 8 edge-groups x 8 col-lanes; nt on streaming accesses ----
// Streaming traffic (csr reads, self-row read, out stores) bypasses L2 so the
// random p-gathers keep the L2 capacity.
__global__ void k_pull(const int* __restrict__ row_start, const int* __restrict__ csr_src,
                       const unsigned short* __restrict__ ob, const float* __restrict__ invd,
                       float* __restrict__ out) {
    int n = blockIdx.x * 4 + (threadIdx.x >> 6);
    if (n >= N_NODES) return;
    int lane = threadIdx.x & 63;
    int g = lane >> 3;
    int c = lane & 7;
    int b = row_start[n], e = row_start[n + 1];
    float acc[8];
    #pragma unroll
    for (int q = 0; q < 8; ++q) acc[q] = 0.0f;
    for (int i = b + g; i < e; i += 8) {
        int s = __builtin_nontemporal_load(&csr_src[i]);
        bf16x8 v = *(const bf16x8*)&ob[(size_t)s * 128 + 64 + c * 8];   // cached gather
        #pragma unroll
        for (int q = 0; q < 8; ++q) acc[q] += bf2f((unsigned short)v[q]);
    }
    #pragma unroll
    for (int q = 0; q < 8; ++q) {
        acc[q] += __shfl_xor(acc[q], 8, 64);
        acc[q] += __shfl_xor(acc[q], 16, 64);
        acc[q] += __shfl_xor(acc[q], 32, 64);
    }
    if (g == 0) {
        float id = invd[n];
        bf16x8 sv = __builtin_nontemporal_load((const bf16x8*)&ob[(size_t)n * 128 + c * 8]);
        f32x4 o0, o1;
        o0[0] = bf2f((unsigned short)sv[0]) + acc[0] * id;
        o0[1] = bf2f((unsigned short)sv[1]) + acc[1] * id;
        o0[2] = bf2f((unsigned short)sv[2]) + acc[2] * id;
        o0[3] = bf2f((unsigned short)sv[3]) + acc[3] * id;
        o1[0] = bf2f((unsigned short)sv[4]) + acc[4] * id;
        o1[1] = bf2f((unsigned short)sv[5]) + acc[5] * id;
        o1[2] = bf2f((unsigned short)sv[6]) + acc[6] * id;
        o1[3] = bf2f((unsigned short)sv[7]) + acc[7] * id;
        __builtin_nontemporal_store(o0, (f32x4*)&out[(size_t)n * OUTF + c * 8]);
        __builtin_nontemporal_store(o1, (f32x4*)&out[(size_t)n * OUTF + c * 8 + 4]);
    }
}

// ---------------- launcher ----------------

static inline size_t al256(size_t v) { return (v + 255) & ~(size_t)255; }

extern "C" void kernel_launch(void* const* d_in, const int* in_sizes, int n_in,
                              void* d_out, int out_size, void* d_ws, size_t ws_size,
                              hipStream_t stream) {
    const float* x   = (const float*)d_in[0];
    const int*   src = (const int*)d_in[1];
    const int*   dst = (const int*)d_in[2];
    const float* W1s = (const float*)d_in[3];
    const float* W1n = (const float*)d_in[4];
    const float* b1  = (const float*)d_in[5];
    const float* W2s = (const float*)d_in[6];
    const float* W2n = (const float*)d_in[7];
    const float* b2  = (const float*)d_in[8];
    float* out = (float*)d_out;

    char* ws = (char*)d_ws;
    size_t off = 0;
    int*   row_start = (int*)(ws + off); off += al256((size_t)(N_NODES + 1) * 4);
    int*   csr_src   = (int*)(ws + off); off += al256((size_t)N_EDGES * 4);
    float* invd      = (float*)(ws + off); off += al256((size_t)N_NODES * 4);
    unsigned short* ob = (unsigned short*)(ws + off); off += al256((size_t)N_NODES * 128 * 2);
    float4* x4       = (float4*)(ws + off); off += al256((size_t)N_NODES * 16);
    float4* hn4      = (float4*)(ws + off); off += al256((size_t)N_NODES * 16);
    unsigned int* pairbuf = (unsigned int*)(ws + off); off += al256((size_t)N_EDGES * 4);
    int*   bukcnt    = (int*)(ws + off); off += al256((size_t)NBUK * 4);
    int*   bukoff    = (int*)(ws + off); off += al256((size_t)(NBUK + 1) * 4);
    int*   bukcur    = (int*)(ws + off); off += al256((size_t)NBUK * 4);
    float* W1t       = (float*)(ws + off); off += al256((size_t)KPAD * 8 * 4);
    unsigned short* W2T = (unsigned short*)(ws + off); off += al256((size_t)128 * KPAD * 2);

    hipMemsetAsync(bukcnt, 0, (size_t)NBUK * 4, stream);

    k_prep<<<NTILE, 256, 0, stream>>>(x, x4, dst, bukcnt, W1s, W1n, b1, W2s, W2n, W1t, W2T);
    k_bukscan<<<1, 256, 0, stream>>>(bukcnt, bukoff, bukcur, row_start);
    k_part<<<NTILE, 256, 0, stream>>>(src, dst, bukoff, bukcur, pairbuf);
    // merged: hist + layer1-agg + scan + row_start/invd/hn4 + scatter
    k_fine<<<NBUK, 512, 0, stream>>>(bukoff, pairbuf, x4, row_start, invd, csr_src, hn4);
    {   // fused layer1+layer2 GEMM (bf16 MFMA) -> unified bf16 row buffer
        int blocks = (N_NODES + 63) / 64;
        k_gemm<<<blocks, 256, 0, stream>>>(x4, hn4, W1t, W2T, b2, ob);
    }
    {   // layer-2 neighbor aggregation (pull, nt-hinted)
        int blocks = (N_NODES + 3) / 4;
        k_pull<<<blocks, 256, 0, stream>>>(row_start, csr_src, ob, invd, out);
    }
}

// Round 12
// 151.886 us; speedup vs baseline: 1.1993x; 1.1993x over previous
//
#include <hip/hip_runtime.h>

#define N_NODES 100000
#define N_EDGES 1600000
#define HID 150
#define KPAD 160
#define OUTF 64
#define BSH 9                          // 512 nodes per bucket
#define BUKN 512                       // nodes per bucket
#define NBUK ((N_NODES + BUKN - 1) / BUKN)   // 196 buckets
#define TILE 4096                      // edges per partition tile
#define NTILE ((N_EDGES + TILE - 1) / TILE)  // 391 tiles

typedef short bf16x8 __attribute__((ext_vector_type(8)));
typedef float f32x4 __attribute__((ext_vector_type(4)));

__device__ __forceinline__ unsigned short f2bf(float f) {
    union { float f; unsigned u; } v; v.f = f;
    unsigned r = (v.u + 0x7FFFu + ((v.u >> 16) & 1u)) >> 16;
    return (unsigned short)r;
}

__device__ __forceinline__ float bf2f(unsigned short b) {
    union { unsigned u; float f; } v;
    v.u = ((unsigned)b) << 16;
    return v.f;
}

// ---------------- prep: pad x -> x4, bucket histogram of dst, W1t/W2T pack ----------------
__global__ __launch_bounds__(256) void k_prep(const float* __restrict__ x,
                                              float4* __restrict__ x4,
                                              const int* __restrict__ dst,
                                              int* __restrict__ bukcnt,
                                              const float* __restrict__ W1s,
                                              const float* __restrict__ W1n,
                                              const float* __restrict__ b1,
                                              const float* __restrict__ W2s,
                                              const float* __restrict__ W2n,
                                              float* __restrict__ W1t,
                                              unsigned short* __restrict__ W2T) {
    __shared__ int cnt[NBUK];
    int tid = threadIdx.x;
    for (int i = tid; i < NBUK; i += 256) cnt[i] = 0;
    int idx = blockIdx.x * 256 + tid;
    if (idx < N_NODES)
        x4[idx] = make_float4(x[idx * 3 + 0], x[idx * 3 + 1], x[idx * 3 + 2], 0.0f);
    if (idx < KPAD) {
        int k = idx;
        bool ok = (k < HID);
        W1t[k * 8 + 0] = ok ? W1s[0 * HID + k] : 0.0f;
        W1t[k * 8 + 1] = ok ? W1s[1 * HID + k] : 0.0f;
        W1t[k * 8 + 2] = ok ? W1s[2 * HID + k] : 0.0f;
        W1t[k * 8 + 3] = ok ? b1[k] : 0.0f;
        W1t[k * 8 + 4] = ok ? W1n[0 * HID + k] : 0.0f;
        W1t[k * 8 + 5] = ok ? W1n[1 * HID + k] : 0.0f;
        W1t[k * 8 + 6] = ok ? W1n[2 * HID + k] : 0.0f;
        W1t[k * 8 + 7] = 0.0f;
    }
    if (idx < 128 * KPAD) {
        int c = idx / KPAD, k = idx - c * KPAD;
        float v = 0.0f;
        if (k < HID) v = (c < 64) ? W2s[k * 64 + c] : W2n[k * 64 + (c - 64)];
        W2T[idx] = f2bf(v);
    }
    __syncthreads();
    int e0 = blockIdx.x * TILE;
    #pragma unroll
    for (int j = 0; j < 16; ++j) {
        int e = e0 + tid + j * 256;
        if (e < N_EDGES) atomicAdd(&cnt[dst[e] >> BSH], 1);
    }
    __syncthreads();
    for (int i = tid; i < NBUK; i += 256)
        if (cnt[i]) atomicAdd(&bukcnt[i], cnt[i]);
}

// ---------------- bucket scan: bukcnt -> bukoff (exclusive), zero bukcur ----------------
__global__ __launch_bounds__(256) void k_bukscan(const int* __restrict__ bukcnt,
                                                 int* __restrict__ bukoff,
                                                 int* __restrict__ bukcur,
                                                 int* __restrict__ row_start) {
    __shared__ int sh[256];
    int t = threadIdx.x;
    int v = (t < NBUK) ? bukcnt[t] : 0;
    sh[t] = v;
    __syncthreads();
    for (int o = 1; o < 256; o <<= 1) {
        int a = sh[t];
        int ap = (t >= o) ? sh[t - o] : 0;
        __syncthreads();
        sh[t] = a + ap;
        __syncthreads();
    }
    if (t < NBUK) { bukoff[t] = sh[t] - v; bukcur[t] = 0; }
    if (t == 255) {
        bukoff[NBUK] = sh[NBUK - 1];
        row_start[N_NODES] = sh[NBUK - 1];
    }
}

// ---------------- multisplit partition: direct bucket-segment writes ----------------
__global__ __launch_bounds__(256) void k_part(const int* __restrict__ src,
                                              const int* __restrict__ dst,
                                              const int* __restrict__ bukoff,
                                              int* __restrict__ bukcur,
                                              unsigned int* __restrict__ pairbuf) {
    __shared__ int cnt[NBUK];
    __shared__ int gbase[NBUK];
    int tid = threadIdx.x;
    int e0 = blockIdx.x * TILE;
    int n = min(TILE, N_EDGES - e0);

    for (int i = tid; i < NBUK; i += 256) cnt[i] = 0;
    __syncthreads();

    int myb[16];
    int mypos[16];
    unsigned int myv[16];
    #pragma unroll
    for (int j = 0; j < 16; ++j) {
        int idx = tid + j * 256;
        myb[j] = -1;
        if (idx < n) {
            int s = src[e0 + idx];
            int d = dst[e0 + idx];
            int b = d >> BSH;
            myb[j] = b;
            myv[j] = ((unsigned int)(d & (BUKN - 1)) << 17) | (unsigned int)s;
            mypos[j] = atomicAdd(&cnt[b], 1);
        }
    }
    __syncthreads();

    if (tid < NBUK) {
        int c = cnt[tid];
        gbase[tid] = c ? (bukoff[tid] + atomicAdd(&bukcur[tid], c)) : 0;
    }
    __syncthreads();

    #pragma unroll
    for (int j = 0; j < 16; ++j) {
        if (myb[j] >= 0)
            pairbuf[gbase[myb[j]] + mypos[j]] = myv[j];
    }
}

// ---------------- merged per-bucket CSR finish: hist + scan + row_start/invd + scatter --
__global__ __launch_bounds__(256) void k_fine(const int* __restrict__ bukoff,
                                              const unsigned int* __restrict__ pairbuf,
                                              int* __restrict__ row_start,
                                              float* __restrict__ invd,
                                              int* __restrict__ csr_src) {
    __shared__ int deg[BUKN];      // counts, later reused as scatter cursors
    __shared__ int scan[256];
    int tid = threadIdx.x;
    int b = blockIdx.x;
    int n0 = b << BSH;
    int lo = bukoff[b], hi = bukoff[b + 1];

    for (int i = tid; i < BUKN; i += 256) deg[i] = 0;
    __syncthreads();
    for (int i = lo + tid; i < hi; i += 256)
        atomicAdd(&deg[pairbuf[i] >> 17], 1);
    __syncthreads();

    int d0 = deg[2 * tid], d1 = deg[2 * tid + 1];
    int pairsum = d0 + d1;
    scan[tid] = pairsum;
    __syncthreads();
    for (int o = 1; o < 256; o <<= 1) {
        int a = scan[tid];
        int ap = (tid >= o) ? scan[tid - o] : 0;
        __syncthreads();
        scan[tid] = a + ap;
        __syncthreads();
    }
    int r0 = lo + scan[tid] - pairsum;
    int r1 = r0 + d0;
    int node0 = n0 + 2 * tid, node1 = node0 + 1;
    if (node0 < N_NODES) { row_start[node0] = r0; invd[node0] = 1.0f / fmaxf((float)d0, 1.0f); }
    if (node1 < N_NODES) { row_start[node1] = r1; invd[node1] = 1.0f / fmaxf((float)d1, 1.0f); }
    __syncthreads();
    deg[2 * tid] = r0;
    deg[2 * tid + 1] = r1;
    __syncthreads();
    for (int i = lo + tid; i < hi; i += 256) {
        unsigned int v = pairbuf[i];
        int dl = v >> 17;
        int ofs = atomicAdd(&deg[dl], 1);
        csr_src[ofs] = (int)(v & 0x1FFFF);
    }
}

// ---------------- layer-1 neighbor mean ----------------

__global__ void k_agg1(const int* __restrict__ row_start, const int* __restrict__ csr_src,
                       const float4* __restrict__ x4, const float* __restrict__ invd,
                       float4* __restrict__ hn4) {
    int wid = (blockIdx.x * blockDim.x + threadIdx.x) >> 6;
    int lane = threadIdx.x & 63;
    int n = wid * 16 + (lane >> 2);
    if (n >= N_NODES) return;
    int sub = lane & 3;
    int b = row_start[n], e = row_start[n + 1];
    float s0 = 0.f, s1 = 0.f, s2 = 0.f;
    for (int i = b + sub; i < e; i += 4) {
        float4 v = x4[csr_src[i]];
        s0 += v.x; s1 += v.y; s2 += v.z;
    }
    s0 += __shfl_xor(s0, 1, 64); s0 += __shfl_xor(s0, 2, 64);
    s1 += __shfl_xor(s1, 1, 64); s1 += __shfl_xor(s1, 2, 64);
    s2 += __shfl_xor(s2, 1, 64); s2 += __shfl_xor(s2, 2, 64);
    if (sub == 0) {
        float id = invd[n];
        hn4[n] = make_float4(s0 * id, s1 * id, s2 * id, 0.0f);
    }
}

// ---------------- fused layer1 + layer2 GEMM via bf16 MFMA ----------------
// Writes one bf16 row per node: ob[node][0..63] = self+b2, ob[node][64..127] = p
#define SHK 168
__global__ __launch_bounds__(256, 4) void k_gemm(
        const float4* __restrict__ x4, const float4* __restrict__ hn4,
        const float* __restrict__ W1t,
        const unsigned short* __restrict__ W2T,
        const float* __restrict__ b2,
        unsigned short* __restrict__ ob) {
    __shared__ unsigned short shA[64 * SHK];   // 21.5 KB
    const int n0 = blockIdx.x * 64;
    const int tid = threadIdx.x;

    {
        int n = tid & 63;
        int node = n0 + n;
        int kbase = 2 * (tid >> 6);
        float4 xs = make_float4(0.f, 0.f, 0.f, 0.f);
        float4 xn = make_float4(0.f, 0.f, 0.f, 0.f);
        if (node < N_NODES) { xs = x4[node]; xn = hn4[node]; }
        #pragma unroll 4
        for (int j = 0; j < 20; ++j) {
            int k = kbase + 8 * j;
            float4 wa0 = *(const float4*)&W1t[k * 8 + 0];
            float4 wb0 = *(const float4*)&W1t[k * 8 + 4];
            float4 wa1 = *(const float4*)&W1t[(k + 1) * 8 + 0];
            float4 wb1 = *(const float4*)&W1t[(k + 1) * 8 + 4];
            float h0 = wa0.w + xs.x * wa0.x + xs.y * wa0.y + xs.z * wa0.z
                             + xn.x * wb0.x + xn.y * wb0.y + xn.z * wb0.z;
            float h1 = wa1.w + xs.x * wa1.x + xs.y * wa1.y + xs.z * wa1.z
                             + xn.x * wb1.x + xn.y * wb1.y + xn.z * wb1.z;
            h0 = fmaxf(h0, 0.0f);
            h1 = fmaxf(h1, 0.0f);
            unsigned int pk = (unsigned int)f2bf(h0) | ((unsigned int)f2bf(h1) << 16);
            *(unsigned int*)&shA[n * SHK + k] = pk;
        }
    }
    __syncthreads();

    const int lane = tid & 63;
    const int w = tid >> 6;
    const int c16 = lane & 15;
    const int quad = lane >> 4;
    const int ko = quad * 8;

    f32x4 acc[8];
    #pragma unroll
    for (int t = 0; t < 8; ++t) acc[t] = (f32x4){0.f, 0.f, 0.f, 0.f};

    #pragma unroll
    for (int ks = 0; ks < 5; ++ks) {
        int k0 = ks * 32;
        bf16x8 a = *(const bf16x8*)&shA[(w * 16 + c16) * SHK + k0 + ko];
        #pragma unroll
        for (int t = 0; t < 8; ++t) {
            bf16x8 b = *(const bf16x8*)&W2T[(t * 16 + c16) * KPAD + k0 + ko];
            acc[t] = __builtin_amdgcn_mfma_f32_16x16x32_bf16(a, b, acc[t], 0, 0, 0);
        }
    }

    const int rbase = n0 + w * 16 + quad * 4;
    #pragma unroll
    for (int t = 0; t < 8; ++t) {
        int cc = t * 16 + c16;
        float badd = (t < 4) ? b2[cc] : 0.0f;
        #pragma unroll
        for (int i = 0; i < 4; ++i) {
            int node = rbase + i;
            if (node < N_NODES) ob[(size_t)node * 128 + cc] = f2bf(acc[t][i] + badd);
        }
    }
}

// ---------------- layer-2 pull: one 8-lane group per node, pipelined edge walk ----------
// Wave = 8 groups; group g owns node n0+g completely. Lane t (0..7) covers cols
// t*8..t*8+7 (16 B). Per edge: one bf16x8 gather per lane; iterations are
// independent -> deep memory pipelining. NO cross-lane reduction needed.
__global__ __launch_bounds__(256) void k_pull(const int* __restrict__ row_start,
                                              const int* __restrict__ csr_src,
                                              const unsigned short* __restrict__ ob,
                                              const float* __restrict__ invd,
                                              float* __restrict__ out) {
    int wid = blockIdx.x * 4 + (threadIdx.x >> 6);   // wave id
    int lane = threadIdx.x & 63;
    int g = lane >> 3;                               // group -> node n0+g
    int t = lane & 7;                                // col chunk
    int n = wid * 8 + g;
    if (n >= N_NODES) return;
    int b = row_start[n];
    int e = row_start[n + 1];

    float acc[8];
    #pragma unroll
    for (int q = 0; q < 8; ++q) acc[q] = 0.0f;

    #pragma unroll 4
    for (int i = b; i < e; ++i) {
        int s = csr_src[i];                          // 8 lanes same addr (broadcast)
        bf16x8 v = *(const bf16x8*)&ob[(size_t)s * 128 + 64 + t * 8];
        #pragma unroll
        for (int q = 0; q < 8; ++q) acc[q] += bf2f((unsigned short)v[q]);
    }

    float id = invd[n];
    bf16x8 sv = *(const bf16x8*)&ob[(size_t)n * 128 + t * 8];
    f32x4 o0, o1;
    o0[0] = bf2f((unsigned short)sv[0]) + acc[0] * id;
    o0[1] = bf2f((unsigned short)sv[1]) + acc[1] * id;
    o0[2] = bf2f((unsigned short)sv[2]) + acc[2] * id;
    o0[3] = bf2f((unsigned short)sv[3]) + acc[3] * id;
    o1[0] = bf2f((unsigned short)sv[4]) + acc[4] * id;
    o1[1] = bf2f((unsigned short)sv[5]) + acc[5] * id;
    o1[2] = bf2f((unsigned short)sv[6]) + acc[6] * id;
    o1[3] = bf2f((unsigned short)sv[7]) + acc[7] * id;
    *(f32x4*)&out[(size_t)n * OUTF + t * 8]     = o0;
    *(f32x4*)&out[(size_t)n * OUTF + t * 8 + 4] = o1;
}

// ---------------- launcher ----------------

static inline size_t al256(size_t v) { return (v + 255) & ~(size_t)255; }

extern "C" void kernel_launch(void* const* d_in, const int* in_sizes, int n_in,
                              void* d_out, int out_size, void* d_ws, size_t ws_size,
                              hipStream_t stream) {
    const float* x   = (const float*)d_in[0];
    const int*   src = (const int*)d_in[1];
    const int*   dst = (const int*)d_in[2];
    const float* W1s = (const float*)d_in[3];
    const float* W1n = (const float*)d_in[4];
    const float* b1  = (const float*)d_in[5];
    const float* W2s = (const float*)d_in[6];
    const float* W2n = (const float*)d_in[7];
    const float* b2  = (const float*)d_in[8];
    float* out = (float*)d_out;

    char* ws = (char*)d_ws;
    size_t off = 0;
    int*   row_start = (int*)(ws + off); off += al256((size_t)(N_NODES + 1) * 4);
    int*   csr_src   = (int*)(ws + off); off += al256((size_t)N_EDGES * 4);
    float* invd      = (float*)(ws + off); off += al256((size_t)N_NODES * 4);
    unsigned short* ob = (unsigned short*)(ws + off); off += al256((size_t)N_NODES * 128 * 2);
    float4* x4       = (float4*)(ws + off); off += al256((size_t)N_NODES * 16);
    float4* hn4      = (float4*)(ws + off); off += al256((size_t)N_NODES * 16);
    unsigned int* pairbuf = (unsigned int*)(ws + off); off += al256((size_t)N_EDGES * 4);
    int*   bukcnt    = (int*)(ws + off); off += al256((size_t)NBUK * 4);
    int*   bukoff    = (int*)(ws + off); off += al256((size_t)(NBUK + 1) * 4);
    int*   bukcur    = (int*)(ws + off); off += al256((size_t)NBUK * 4);
    float* W1t       = (float*)(ws + off); off += al256((size_t)KPAD * 8 * 4);
    unsigned short* W2T = (unsigned short*)(ws + off); off += al256((size_t)128 * KPAD * 2);

    hipMemsetAsync(bukcnt, 0, (size_t)NBUK * 4, stream);

    k_prep<<<NTILE, 256, 0, stream>>>(x, x4, dst, bukcnt, W1s, W1n, b1, W2s, W2n, W1t, W2T);
    k_bukscan<<<1, 256, 0, stream>>>(bukcnt, bukoff, bukcur, row_start);
    k_part<<<NTILE, 256, 0, stream>>>(src, dst, bukoff, bukcur, pairbuf);
    k_fine<<<NBUK, 256, 0, stream>>>(bukoff, pairbuf, row_start, invd, csr_src);
    {   // layer-1 neighbor mean
        int waves = (N_NODES + 15) / 16;
        int blocks = (waves * 64 + 255) / 256;
        k_agg1<<<blocks, 256, 0, stream>>>(row_start, csr_src, x4, invd, hn4);
    }
    {   // fused layer1+layer2 GEMM (bf16 MFMA) -> unified bf16 row buffer
        int blocks = (N_NODES + 63) / 64;
        k_gemm<<<blocks, 256, 0, stream>>>(x4, hn4, W1t, W2T, b2, ob);
    }
    {   // layer-2 neighbor aggregation (pull: 8 nodes/wave, pipelined)
        int blocks = (N_NODES + 31) / 32;
        k_pull<<<blocks, 256, 0, stream>>>(row_start, csr_src, ob, invd, out);
    }
}

// Round 13
// 146.270 us; speedup vs baseline: 1.2454x; 1.0384x over previous
//
#include <hip/hip_runtime.h>

#define N_NODES 100000
#define N_EDGES 1600000
#define HID 150
#define KPAD 160
#define OUTF 64
#define BSH 9                          // 512 nodes per bucket
#define BUKN 512                       // nodes per bucket
#define NBUK ((N_NODES + BUKN - 1) / BUKN)   // 196 buckets
#define CAP 10240                      // arena capacity per bucket (exp ~8.2K, sigma ~90)
#define TILE 4096                      // edges per partition tile
#define NTILE ((N_EDGES + TILE - 1) / TILE)  // 391 tiles

typedef short bf16x8 __attribute__((ext_vector_type(8)));
typedef float f32x4 __attribute__((ext_vector_type(4)));

__device__ __forceinline__ unsigned short f2bf(float f) {
    union { float f; unsigned u; } v; v.f = f;
    unsigned r = (v.u + 0x7FFFu + ((v.u >> 16) & 1u)) >> 16;
    return (unsigned short)r;
}

__device__ __forceinline__ float bf2f(unsigned short b) {
    union { unsigned u; float f; } v;
    v.u = ((unsigned)b) << 16;
    return v.f;
}

// ---------------- init (1 block): zero bukcnt, pack W1t + W2T ----------------
__global__ __launch_bounds__(256) void k_init(const float* __restrict__ W1s,
                                              const float* __restrict__ W1n,
                                              const float* __restrict__ b1,
                                              const float* __restrict__ W2s,
                                              const float* __restrict__ W2n,
                                              float* __restrict__ W1t,
                                              unsigned short* __restrict__ W2T,
                                              int* __restrict__ bukcnt) {
    int tid = threadIdx.x;
    if (tid < NBUK) bukcnt[tid] = 0;
    for (int k = tid; k < KPAD; k += 256) {
        bool ok = (k < HID);
        W1t[k * 8 + 0] = ok ? W1s[0 * HID + k] : 0.0f;
        W1t[k * 8 + 1] = ok ? W1s[1 * HID + k] : 0.0f;
        W1t[k * 8 + 2] = ok ? W1s[2 * HID + k] : 0.0f;
        W1t[k * 8 + 3] = ok ? b1[k] : 0.0f;
        W1t[k * 8 + 4] = ok ? W1n[0 * HID + k] : 0.0f;
        W1t[k * 8 + 5] = ok ? W1n[1 * HID + k] : 0.0f;
        W1t[k * 8 + 6] = ok ? W1n[2 * HID + k] : 0.0f;
        W1t[k * 8 + 7] = 0.0f;
    }
    for (int idx = tid; idx < 128 * KPAD; idx += 256) {
        int c = idx / KPAD, k = idx - c * KPAD;
        float v = 0.0f;
        if (k < HID) v = (c < 64) ? W2s[k * 64 + c] : W2n[k * 64 + (c - 64)];
        W2T[idx] = f2bf(v);
    }
}

// ---------------- partition: x4 pad + bin edges into per-bucket arenas ----------------
__global__ __launch_bounds__(256) void k_part(const float* __restrict__ x,
                                              float4* __restrict__ x4,
                                              const int* __restrict__ src,
                                              const int* __restrict__ dst,
                                              int* __restrict__ bukcnt,
                                              unsigned int* __restrict__ pairbuf) {
    __shared__ int cnt[NBUK];
    __shared__ int gbase[NBUK];
    int tid = threadIdx.x;
    int idx = blockIdx.x * 256 + tid;
    if (idx < N_NODES)
        x4[idx] = make_float4(x[idx * 3 + 0], x[idx * 3 + 1], x[idx * 3 + 2], 0.0f);

    int e0 = blockIdx.x * TILE;
    int n = min(TILE, N_EDGES - e0);

    for (int i = tid; i < NBUK; i += 256) cnt[i] = 0;
    __syncthreads();

    int myb[16];
    int mypos[16];
    unsigned int myv[16];
    #pragma unroll
    for (int j = 0; j < 16; ++j) {
        int ei = tid + j * 256;
        myb[j] = -1;
        if (ei < n) {
            int s = src[e0 + ei];
            int d = dst[e0 + ei];
            int b = d >> BSH;
            myb[j] = b;
            myv[j] = ((unsigned int)(d & (BUKN - 1)) << 17) | (unsigned int)s;
            mypos[j] = atomicAdd(&cnt[b], 1);
        }
    }
    __syncthreads();

    if (tid < NBUK) {
        int c = cnt[tid];
        gbase[tid] = c ? (tid * CAP + atomicAdd(&bukcnt[tid], c)) : 0;
    }
    __syncthreads();

    #pragma unroll
    for (int j = 0; j < 16; ++j) {
        if (myb[j] >= 0)
            pairbuf[gbase[myb[j]] + mypos[j]] = myv[j];
    }
}

// ---------------- per-bucket CSR finish: hist + scan + rows/invd + scatter ----------
// 512 threads: thread t owns node n0+t.
__global__ __launch_bounds__(512) void k_fine(const int* __restrict__ bukcnt,
                                              const unsigned int* __restrict__ pairbuf,
                                              int2* __restrict__ rows,
                                              float* __restrict__ invd,
                                              int* __restrict__ csr_src) {
    __shared__ int deg[BUKN];      // counts, later reused as scatter cursors
    __shared__ int sc[BUKN];
    int tid = threadIdx.x;
    int b = blockIdx.x;
    int n0 = b << BSH;
    int lo = b * CAP;
    int hi = lo + bukcnt[b];

    deg[tid] = 0;
    __syncthreads();
    for (int i = lo + tid; i < hi; i += 512)
        atomicAdd(&deg[pairbuf[i] >> 17], 1);
    __syncthreads();

    int d = deg[tid];
    sc[tid] = d;
    __syncthreads();
    for (int o = 1; o < 512; o <<= 1) {
        int a = sc[tid];
        int ap = (tid >= o) ? sc[tid - o] : 0;
        __syncthreads();
        sc[tid] = a + ap;
        __syncthreads();
    }
    int r = lo + sc[tid] - d;
    int node = n0 + tid;
    if (node < N_NODES) {
        rows[node] = make_int2(r, r + d);
        invd[node] = 1.0f / fmaxf((float)d, 1.0f);
    }
    __syncthreads();
    deg[tid] = r;     // reuse as cursor
    __syncthreads();
    for (int i = lo + tid; i < hi; i += 512) {
        unsigned int v = pairbuf[i];
        int dl = v >> 17;
        int ofs = atomicAdd(&deg[dl], 1);
        csr_src[ofs] = (int)(v & 0x1FFFF);
    }
}

// ---------------- layer-1 neighbor mean ----------------

__global__ void k_agg1(const int2* __restrict__ rows, const int* __restrict__ csr_src,
                       const float4* __restrict__ x4, const float* __restrict__ invd,
                       float4* __restrict__ hn4) {
    int wid = (blockIdx.x * blockDim.x + threadIdx.x) >> 6;
    int lane = threadIdx.x & 63;
    int n = wid * 16 + (lane >> 2);
    if (n >= N_NODES) return;
    int sub = lane & 3;
    int2 re = rows[n];
    float s0 = 0.f, s1 = 0.f, s2 = 0.f;
    for (int i = re.x + sub; i < re.y; i += 4) {
        float4 v = x4[csr_src[i]];
        s0 += v.x; s1 += v.y; s2 += v.z;
    }
    s0 += __shfl_xor(s0, 1, 64); s0 += __shfl_xor(s0, 2, 64);
    s1 += __shfl_xor(s1, 1, 64); s1 += __shfl_xor(s1, 2, 64);
    s2 += __shfl_xor(s2, 1, 64); s2 += __shfl_xor(s2, 2, 64);
    if (sub == 0) {
        float id = invd[n];
        hn4[n] = make_float4(s0 * id, s1 * id, s2 * id, 0.0f);
    }
}

// ---------------- fused layer1 + layer2 GEMM via bf16 MFMA ----------------
// Writes one bf16 row per node: ob[node][0..63] = self+b2, ob[node][64..127] = p
#define SHK 168
__global__ __launch_bounds__(256, 4) void k_gemm(
        const float4* __restrict__ x4, const float4* __restrict__ hn4,
        const float* __restrict__ W1t,
        const unsigned short* __restrict__ W2T,
        const float* __restrict__ b2,
        unsigned short* __restrict__ ob) {
    __shared__ unsigned short shA[64 * SHK];   // 21.5 KB
    const int n0 = blockIdx.x * 64;
    const int tid = threadIdx.x;

    {
        int n = tid & 63;
        int node = n0 + n;
        int kbase = 2 * (tid >> 6);
        float4 xs = make_float4(0.f, 0.f, 0.f, 0.f);
        float4 xn = make_float4(0.f, 0.f, 0.f, 0.f);
        if (node < N_NODES) { xs = x4[node]; xn = hn4[node]; }
        #pragma unroll 4
        for (int j = 0; j < 20; ++j) {
            int k = kbase + 8 * j;
            float4 wa0 = *(const float4*)&W1t[k * 8 + 0];
            float4 wb0 = *(const float4*)&W1t[k * 8 + 4];
            float4 wa1 = *(const float4*)&W1t[(k + 1) * 8 + 0];
            float4 wb1 = *(const float4*)&W1t[(k + 1) * 8 + 4];
            float h0 = wa0.w + xs.x * wa0.x + xs.y * wa0.y + xs.z * wa0.z
                             + xn.x * wb0.x + xn.y * wb0.y + xn.z * wb0.z;
            float h1 = wa1.w + xs.x * wa1.x + xs.y * wa1.y + xs.z * wa1.z
                             + xn.x * wb1.x + xn.y * wb1.y + xn.z * wb1.z;
            h0 = fmaxf(h0, 0.0f);
            h1 = fmaxf(h1, 0.0f);
            unsigned int pk = (unsigned int)f2bf(h0) | ((unsigned int)f2bf(h1) << 16);
            *(unsigned int*)&shA[n * SHK + k] = pk;
        }
    }
    __syncthreads();

    const int lane = tid & 63;
    const int w = tid >> 6;
    const int c16 = lane & 15;
    const int quad = lane >> 4;
    const int ko = quad * 8;

    f32x4 acc[8];
    #pragma unroll
    for (int t = 0; t < 8; ++t) acc[t] = (f32x4){0.f, 0.f, 0.f, 0.f};

    #pragma unroll
    for (int ks = 0; ks < 5; ++ks) {
        int k0 = ks * 32;
        bf16x8 a = *(const bf16x8*)&shA[(w * 16 + c16) * SHK + k0 + ko];
        #pragma unroll
        for (int t = 0; t < 8; ++t) {
            bf16x8 b = *(const bf16x8*)&W2T[(t * 16 + c16) * KPAD + k0 + ko];
            acc[t] = __builtin_amdgcn_mfma_f32_16x16x32_bf16(a, b, acc[t], 0, 0, 0);
        }
    }

    const int rbase = n0 + w * 16 + quad * 4;
    #pragma unroll
    for (int t = 0; t < 8; ++t) {
        int cc = t * 16 + c16;
        float badd = (t < 4) ? b2[cc] : 0.0f;
        #pragma unroll
        for (int i = 0; i < 4; ++i) {
            int node = rbase + i;
            if (node < N_NODES) ob[(size_t)node * 128 + cc] = f2bf(acc[t][i] + badd);
        }
    }
}

// ---------------- layer-2 pull: one 8-lane group per node, pipelined edge walk ----------
__global__ __launch_bounds__(256) void k_pull(const int2* __restrict__ rows,
                                              const int* __restrict__ csr_src,
                                              const unsigned short* __restrict__ ob,
                                              const float* __restrict__ invd,
                                              float* __restrict__ out) {
    int wid = blockIdx.x * 4 + (threadIdx.x >> 6);   // wave id
    int lane = threadIdx.x & 63;
    int g = lane >> 3;                               // group -> node
    int t = lane & 7;                                // col chunk
    int n = wid * 8 + g;
    if (n >= N_NODES) return;
    int2 re = rows[n];

    float acc[8];
    #pragma unroll
    for (int q = 0; q < 8; ++q) acc[q] = 0.0f;

    #pragma unroll 4
    for (int i = re.x; i < re.y; ++i) {
        int s = csr_src[i];                          // 8 lanes same addr (broadcast)
        bf16x8 v = *(const bf16x8*)&ob[(size_t)s * 128 + 64 + t * 8];
        #pragma unroll
        for (int q = 0; q < 8; ++q) acc[q] += bf2f((unsigned short)v[q]);
    }

    float id = invd[n];
    bf16x8 sv = *(const bf16x8*)&ob[(size_t)n * 128 + t * 8];
    f32x4 o0, o1;
    o0[0] = bf2f((unsigned short)sv[0]) + acc[0] * id;
    o0[1] = bf2f((unsigned short)sv[1]) + acc[1] * id;
    o0[2] = bf2f((unsigned short)sv[2]) + acc[2] * id;
    o0[3] = bf2f((unsigned short)sv[3]) + acc[3] * id;
    o1[0] = bf2f((unsigned short)sv[4]) + acc[4] * id;
    o1[1] = bf2f((unsigned short)sv[5]) + acc[5] * id;
    o1[2] = bf2f((unsigned short)sv[6]) + acc[6] * id;
    o1[3] = bf2f((unsigned short)sv[7]) + acc[7] * id;
    *(f32x4*)&out[(size_t)n * OUTF + t * 8]     = o0;
    *(f32x4*)&out[(size_t)n * OUTF + t * 8 + 4] = o1;
}

// ---------------- launcher ----------------

static inline size_t al256(size_t v) { return (v + 255) & ~(size_t)255; }

extern "C" void kernel_launch(void* const* d_in, const int* in_sizes, int n_in,
                              void* d_out, int out_size, void* d_ws, size_t ws_size,
                              hipStream_t stream) {
    const float* x   = (const float*)d_in[0];
    const int*   src = (const int*)d_in[1];
    const int*   dst = (const int*)d_in[2];
    const float* W1s = (const float*)d_in[3];
    const float* W1n = (const float*)d_in[4];
    const float* b1  = (const float*)d_in[5];
    const float* W2s = (const float*)d_in[6];
    const float* W2n = (const float*)d_in[7];
    const float* b2  = (const float*)d_in[8];
    float* out = (float*)d_out;

    char* ws = (char*)d_ws;
    size_t off = 0;
    int2*  rows      = (int2*)(ws + off); off += al256((size_t)N_NODES * 8);
    int*   csr_src   = (int*)(ws + off); off += al256((size_t)NBUK * CAP * 4);
    float* invd      = (float*)(ws + off); off += al256((size_t)N_NODES * 4);
    unsigned short* ob = (unsigned short*)(ws + off); off += al256((size_t)N_NODES * 128 * 2);
    float4* x4       = (float4*)(ws + off); off += al256((size_t)N_NODES * 16);
    float4* hn4      = (float4*)(ws + off); off += al256((size_t)N_NODES * 16);
    unsigned int* pairbuf = (unsigned int*)(ws + off); off += al256((size_t)NBUK * CAP * 4);
    int*   bukcnt    = (int*)(ws + off); off += al256((size_t)NBUK * 4);
    float* W1t       = (float*)(ws + off); off += al256((size_t)KPAD * 8 * 4);
    unsigned short* W2T = (unsigned short*)(ws + off); off += al256((size_t)128 * KPAD * 2);

    // 1. init: zero bukcnt + pack weights (replaces hipMemsetAsync + old k_prep pack)
    k_init<<<1, 256, 0, stream>>>(W1s, W1n, b1, W2s, W2n, W1t, W2T, bukcnt);
    // 2. partition into per-bucket arenas (+ x4 pad)
    k_part<<<NTILE, 256, 0, stream>>>(x, x4, src, dst, bukcnt, pairbuf);
    // 3. per-bucket CSR finish
    k_fine<<<NBUK, 512, 0, stream>>>(bukcnt, pairbuf, rows, invd, csr_src);
    // 4. layer-1 neighbor mean
    {
        int waves = (N_NODES + 15) / 16;
        int blocks = (waves * 64 + 255) / 256;
        k_agg1<<<blocks, 256, 0, stream>>>(rows, csr_src, x4, invd, hn4);
    }
    // 5. fused layer1+layer2 GEMM (bf16 MFMA)
    {
        int blocks = (N_NODES + 63) / 64;
        k_gemm<<<blocks, 256, 0, stream>>>(x4, hn4, W1t, W2T, b2, ob);
    }
    // 6. layer-2 pull
    {
        int blocks = (N_NODES + 31) / 32;
        k_pull<<<blocks, 256, 0, stream>>>(rows, csr_src, ob, invd, out);
    }
}